// Round 8
// baseline (456.322 us; speedup 1.0000x reference)
//
#include <hip/hip_runtime.h>

// GAT layer, N=8192, F_IN=256, F_OUT=128.
// K1 wh: Wh = h@W (fp32 VALU) + WhT (f16 transposed [c][j]).
// K2 f12: f1 = Wh@a1, f2 = Wh@a2.
// K3 attn: FIFO-compatible VGPR pipeline. RPB=32 rows, JSPLIT=2 -> 512 blocks
//   (2/CU, 8 waves/CU). Per iter, issue order: [bfr(c) x8, L2-hot]
//   [adj(c+1)+f2(c+1) x6, NT HBM]; adj(c) is oldest in FIFO, so the
//   compiler's wait for scores = vmcnt(14) and for MFMA = vmcnt(6) BOTH
//   leave adj(c+1) in flight across compute -> one HBM latency amortized
//   over an entire iteration instead of paid per iteration (r7 flaw).
//   acc 2x8 floatx4 + asum; unroll 2 rotates the double buffers.
// K4 comb: sum 2 partials, normalize.
// NOTE: dur_us includes ~240us harness reset (1GiB ws fill + 256MB adj
// restore) we cannot touch; structural floor ~300us.

#define N_NODES 8192
#define F_IN 256
#define F_OUT 128
#define RPB 32                      // rows per block (2 MFMA row-tiles)
#define JCH 128                     // j per chunk (split 4 ways by waves)
#define JSPLIT 2
#define JRANGE (N_NODES / JSPLIT)   // 4096
#define NCH (JRANGE / JCH)          // 32 iterations

typedef _Float16 half8 __attribute__((ext_vector_type(8)));
typedef float floatx4 __attribute__((ext_vector_type(4)));
typedef float f32x4 __attribute__((ext_vector_type(4)));
typedef int i32x4 __attribute__((ext_vector_type(4)));

__device__ __align__(16) float g_Wh[N_NODES * F_OUT];                  // 4 MB
__device__ __align__(16) _Float16 g_WhT[(size_t)F_OUT * N_NODES];      // 2 MB
__device__ __align__(16) float g_f1[N_NODES];
__device__ __align__(16) float g_f2[N_NODES];
__device__ __align__(16) float g_part[JSPLIT][N_NODES * F_OUT];        // 8 MB
__device__ __align__(16) float g_spart[JSPLIT][N_NODES];               // 64 KB

// ---------------- Kernel A: Wh = h @ W ----------------
__global__ __launch_bounds__(256, 2) void wh_kernel(
    const float* __restrict__ h, const float* __restrict__ W) {
  __shared__ float hT[F_IN][20];  // pad 20 keeps &hT[k][rg*8] 16B-aligned
  const int t = threadIdx.x;
  const int i0 = blockIdx.x * 16;
  {
    const int row = t >> 4;   // 0..15
    const int fu = t & 15;    // float4 unit
#pragma unroll
    for (int r = 0; r < 4; ++r) {
      const int ku = r * 16 + fu;  // 0..63
      const float4 v = *(const float4*)(h + (size_t)(i0 + row) * F_IN + ku * 4);
      hT[ku * 4 + 0][row] = v.x; hT[ku * 4 + 1][row] = v.y;
      hT[ku * 4 + 2][row] = v.z; hT[ku * 4 + 3][row] = v.w;
    }
  }
  __syncthreads();
  const int c = t & 127;
  const int rg = t >> 7;   // 8 rows per thread
  float acc[8];
#pragma unroll
  for (int r = 0; r < 8; ++r) acc[r] = 0.f;
#pragma unroll 8
  for (int k = 0; k < F_IN; ++k) {
    const float wv = W[k * F_OUT + c];
    const float4 x0 = *(const float4*)(&hT[k][rg * 8]);
    const float4 x1 = *(const float4*)(&hT[k][rg * 8 + 4]);
    acc[0] = fmaf(x0.x, wv, acc[0]); acc[1] = fmaf(x0.y, wv, acc[1]);
    acc[2] = fmaf(x0.z, wv, acc[2]); acc[3] = fmaf(x0.w, wv, acc[3]);
    acc[4] = fmaf(x1.x, wv, acc[4]); acc[5] = fmaf(x1.y, wv, acc[5]);
    acc[6] = fmaf(x1.z, wv, acc[6]); acc[7] = fmaf(x1.w, wv, acc[7]);
  }
#pragma unroll
  for (int r = 0; r < 8; ++r)
    g_Wh[(size_t)(i0 + rg * 8 + r) * F_OUT + c] = acc[r];
  union { _Float16 hh[8]; uint4 u4; } pk;
#pragma unroll
  for (int r = 0; r < 8; ++r) pk.hh[r] = (_Float16)acc[r];
  *(uint4*)(g_WhT + (size_t)c * N_NODES + i0 + rg * 8) = pk.u4;
}

// ---------------- Kernel B: f1 = Wh@a1, f2 = Wh@a2 ----------------
__global__ __launch_bounds__(256) void f12_kernel(const float* __restrict__ a) {
  const int t = threadIdx.x;
  const int row = blockIdx.x * 2 + (t >> 7);
  const int c = t & 127;
  const float wh = g_Wh[(size_t)row * F_OUT + c];
  float p1 = wh * a[c];
  float p2 = wh * a[F_OUT + c];
  for (int o = 32; o > 0; o >>= 1) {
    p1 += __shfl_down(p1, o, 64);
    p2 += __shfl_down(p2, o, 64);
  }
  __shared__ float s1[4], s2[4];
  const int w = t >> 6;
  if ((t & 63) == 0) { s1[w] = p1; s2[w] = p2; }
  __syncthreads();
  if ((t & 127) == 0) {
    g_f1[row] = s1[w] + s1[w + 1];
    g_f2[row] = s2[w] + s2[w + 1];
  }
}

// ---------------- Kernel C: fused attention (partials) ----------------
__device__ __forceinline__ float score_p(int a, float f2v, float f1r) {
  float s = f1r + f2v;
  s = fmaxf(s, 0.2f * s);  // leaky_relu, alpha=0.2<1
  float arg = (a > 0) ? fmaf(s, 1.44269504088896f, -16.0f) : -1.0e5f;
  return __builtin_amdgcn_exp2f(arg);  // masked -> 0; 2^-16 scale cancels
}

__global__ __launch_bounds__(256, 2) void gat_attn_kernel(const int* __restrict__ adj) {
  const int t = threadIdx.x;
  const int wave = t >> 6;
  const int lane = t & 63;
  const int mrow = lane & 15;
  const int quad = lane >> 4;
  const int i0 = blockIdx.x * RPB;
  const int js = blockIdx.y;
  const int jbase = js * JRANGE;
  const int jloc = wave * 32 + quad * 8;   // wave's j-slice within chunk

  const float f1r0 = g_f1[i0 + mrow];
  const float f1r1 = g_f1[i0 + 16 + mrow];

  half8 ones;
#pragma unroll
  for (int e = 0; e < 8; ++e) ones[e] = (_Float16)1;

  floatx4 acc[2][8];   // 64 VGPRs
  floatx4 asum[2];
#pragma unroll
  for (int tl = 0; tl < 2; ++tl) {
    asum[tl] = (floatx4)0.f;
#pragma unroll
    for (int ct = 0; ct < 8; ++ct) acc[tl][ct] = (floatx4)0.f;
  }

  const int* ap0 = adj + (size_t)(i0 + mrow) * N_NODES + jbase + jloc;
  const int* ap1 = adj + (size_t)(i0 + 16 + mrow) * N_NODES + jbase + jloc;

  // double-buffered adj + f2 (VGPR), preload chunk 0
  i32x4 A0[2][2], A1[2][2];
  f32x4 Fb[2][2];
  A0[0][0] = __builtin_nontemporal_load((const i32x4*)ap0);
  A0[0][1] = __builtin_nontemporal_load((const i32x4*)ap0 + 1);
  A1[0][0] = __builtin_nontemporal_load((const i32x4*)ap1);
  A1[0][1] = __builtin_nontemporal_load((const i32x4*)ap1 + 1);
  Fb[0][0] = *(const f32x4*)(g_f2 + jbase + jloc);
  Fb[0][1] = *(const f32x4*)(g_f2 + jbase + jloc + 4);

#pragma unroll 2
  for (int c = 0; c < NCH; ++c) {
    const int b = c & 1, nb = b ^ 1;
    const int jglob = jbase + c * JCH + jloc;

    // (1) bfr(c): L2-hot loads, issued FIRST so their wait (vmcnt(6)) leaves
    //     the adj(c+1) prefetch below in flight.
    half8 bfr[8];
#pragma unroll
    for (int ct = 0; ct < 8; ++ct)
      bfr[ct] = *(const half8*)(g_WhT + (size_t)(ct * 16 + mrow) * N_NODES + jglob);

    // (2) adj(c+1) + f2(c+1): NT HBM, in flight across this iter's compute.
    if (c + 1 < NCH) {
      A0[nb][0] = __builtin_nontemporal_load((const i32x4*)(ap0 + (c + 1) * JCH));
      A0[nb][1] = __builtin_nontemporal_load((const i32x4*)(ap0 + (c + 1) * JCH) + 1);
      A1[nb][0] = __builtin_nontemporal_load((const i32x4*)(ap1 + (c + 1) * JCH));
      A1[nb][1] = __builtin_nontemporal_load((const i32x4*)(ap1 + (c + 1) * JCH) + 1);
      Fb[nb][0] = *(const f32x4*)(g_f2 + jglob + JCH);
      Fb[nb][1] = *(const f32x4*)(g_f2 + jglob + JCH + 4);
    }

    // (3) scores from adj(c)/f2(c) (oldest in FIFO -> vmcnt(14))
    half8 af0, af1;
#pragma unroll
    for (int e = 0; e < 4; ++e) {
      af0[e]     = (_Float16)score_p(A0[b][0][e], Fb[b][0][e], f1r0);
      af0[4 + e] = (_Float16)score_p(A0[b][1][e], Fb[b][1][e], f1r0);
      af1[e]     = (_Float16)score_p(A1[b][0][e], Fb[b][0][e], f1r1);
      af1[4 + e] = (_Float16)score_p(A1[b][1][e], Fb[b][1][e], f1r1);
    }

    // (4) MFMA (waits bfr(c) = vmcnt(6); adj(c+1) stays in flight)
#pragma unroll
    for (int ct = 0; ct < 8; ++ct) {
      acc[0][ct] = __builtin_amdgcn_mfma_f32_16x16x32_f16(af0, bfr[ct], acc[0][ct], 0, 0, 0);
      acc[1][ct] = __builtin_amdgcn_mfma_f32_16x16x32_f16(af1, bfr[ct], acc[1][ct], 0, 0, 0);
    }
    asum[0] = __builtin_amdgcn_mfma_f32_16x16x32_f16(af0, ones, asum[0], 0, 0, 0);
    asum[1] = __builtin_amdgcn_mfma_f32_16x16x32_f16(af1, ones, asum[1], 0, 0, 0);
  }

  // -------- epilogue: cross-wave j-reduction via LDS --------
  __shared__ float ldsO[RPB][F_OUT];   // 16 KB
  __shared__ float ldsS[4][RPB];       // 512 B

  if (mrow == 0) {
#pragma unroll
    for (int tl = 0; tl < 2; ++tl)
#pragma unroll
      for (int r = 0; r < 4; ++r)
        ldsS[wave][tl * 16 + quad * 4 + r] = asum[tl][r];
  }
  for (int w = 0; w < 4; ++w) {
    if (wave == w) {
#pragma unroll
      for (int tl = 0; tl < 2; ++tl)
#pragma unroll
        for (int ct = 0; ct < 8; ++ct)
#pragma unroll
          for (int r = 0; r < 4; ++r) {
            // C/D: row = quad*4+r, col = ct*16+mrow (HW-verified r2-r7)
            float* p = &ldsO[tl * 16 + quad * 4 + r][ct * 16 + mrow];
            if (w == 0) *p = acc[tl][ct][r];
            else        *p += acc[tl][ct][r];
          }
    }
    __syncthreads();
  }
  {
    const int row = t >> 3;          // 0..31
    const int c0 = (t & 7) * 16;     // 8 segs of 16 cols
    float* dst = g_part[js] + (size_t)(i0 + row) * F_OUT + c0;
#pragma unroll
    for (int q = 0; q < 4; ++q)
      *(f32x4*)(dst + q * 4) = *(const f32x4*)(&ldsO[row][c0 + q * 4]);
    if ((t & 7) == 0)
      g_spart[js][i0 + row] = ldsS[0][row] + ldsS[1][row] +
                              ldsS[2][row] + ldsS[3][row];
  }
}

// ---------------- Kernel D: combine partials + normalize ----------------
__global__ __launch_bounds__(256) void comb_kernel(float* __restrict__ out) {
  const int u = blockIdx.x * 256 + threadIdx.x;  // float4 unit
  const int row = u >> 5;                        // 32 float4 per row
  const float s = g_spart[0][row] + g_spart[1][row];
  const f32x4 v = ((const f32x4*)g_part[0])[u] + ((const f32x4*)g_part[1])[u];
  ((f32x4*)out)[u] = v * (1.0f / s);
}

extern "C" void kernel_launch(void* const* d_in, const int* in_sizes, int n_in,
                              void* d_out, int out_size, void* d_ws, size_t ws_size,
                              hipStream_t stream) {
  const float* h = (const float*)d_in[0];
  const int* adj = (const int*)d_in[1];
  const float* W = (const float*)d_in[2];
  const float* a = (const float*)d_in[3];
  float* out = (float*)d_out;
  (void)d_ws; (void)ws_size;

  wh_kernel<<<dim3(N_NODES / 16), dim3(256), 0, stream>>>(h, W);
  f12_kernel<<<dim3(N_NODES / 2), dim3(256), 0, stream>>>(a);
  gat_attn_kernel<<<dim3(N_NODES / RPB, JSPLIT), dim3(256), 0, stream>>>(adj);
  comb_kernel<<<dim3(N_NODES * F_OUT / 4 / 256), dim3(256), 0, stream>>>(out);
}